// Round 1
// baseline (116.358 us; speedup 1.0000x reference)
//
#include <hip/hip_runtime.h>

#define T_DIM 256
#define B_DIM 8
#define DIN   256
#define DM    256
#define A_DIM 128
#define S_TILE 4
#define NEG_INF_F (-1e30f)

// ---------------- Kernel A: projections ----------------
// block per (t,b): threads 0..127 compute IP[t,b,a] (a=tid),
// threads 128..255 compute MP transposed -> MPt[b,a,t] (a=tid-128).
__global__ __launch_bounds__(256) void proj_kernel(
    const float* __restrict__ input, const float* __restrict__ memory,
    const float* __restrict__ Wi, const float* __restrict__ Wm,
    float* __restrict__ IP, float* __restrict__ MPt)
{
    __shared__ float xin[DIN];
    __shared__ float xmem[DM];
    const int tb  = blockIdx.x;
    const int t   = tb / B_DIM;
    const int b   = tb % B_DIM;
    const int tid = threadIdx.x;

    xin[tid]  = input[(t * B_DIM + b) * DIN + tid];
    xmem[tid] = memory[(t * B_DIM + b) * DM + tid];
    __syncthreads();

    if (tid < A_DIM) {
        const int a = tid;
        float acc = 0.f;
        #pragma unroll 8
        for (int d = 0; d < DIN; ++d)
            acc = fmaf(xin[d], Wi[d * A_DIM + a], acc);
        IP[(t * B_DIM + b) * A_DIM + a] = acc;
    } else {
        const int a = tid - A_DIM;
        float acc = 0.f;
        #pragma unroll 8
        for (int d = 0; d < DM; ++d)
            acc = fmaf(xmem[d], Wm[d * A_DIM + a], acc);
        MPt[(b * A_DIM + a) * T_DIM + t] = acc;
    }
}

__device__ inline float warp_red_max(float v) {
    #pragma unroll
    for (int o = 32; o > 0; o >>= 1) v = fmaxf(v, __shfl_xor(v, o, 64));
    return v;
}
__device__ inline float warp_red_sum(float v) {
    #pragma unroll
    for (int o = 32; o > 0; o >>= 1) v += __shfl_xor(v, o, 64);
    return v;
}

// ---------------- Kernel B: logits + softmax + context + concat ----------------
// block per (b, s-tile of S_TILE). 256 threads.
// Phase 1: thread = key index t. Phase 2: thread = feature index d.
__global__ __launch_bounds__(256) void attn_kernel(
    const float* __restrict__ input, const int* __restrict__ mask,
    const float* __restrict__ v, const float* __restrict__ IP,
    const float* __restrict__ MPt, float* __restrict__ out)
{
    __shared__ float ip_s[S_TILE][A_DIM];
    __shared__ float vs[A_DIM];
    __shared__ float sc[S_TILE][T_DIM];
    __shared__ float red[4];

    const int blk = blockIdx.x;
    const int b   = blk % B_DIM;
    const int s0  = (blk / B_DIM) * S_TILE;
    const int tid = threadIdx.x;
    const int lane = tid & 63;
    const int wave = tid >> 6;

    if (tid < A_DIM) vs[tid] = v[tid];
    for (int i = tid; i < S_TILE * A_DIM; i += 256) {
        const int s = i / A_DIM, a = i % A_DIM;
        ip_s[s][a] = IP[((s0 + s) * B_DIM + b) * A_DIM + a];
    }
    __syncthreads();

    // ---- Phase 1: logits. thread tid = key t. a outer, s inner (MP loaded once). ----
    const int t = tid;
    float acc[S_TILE];
    #pragma unroll
    for (int s = 0; s < S_TILE; ++s) acc[s] = 0.f;

    const float* mp_base = MPt + (size_t)(b * A_DIM) * T_DIM + t;
    #pragma unroll 4
    for (int a = 0; a < A_DIM; ++a) {
        const float mp = mp_base[(size_t)a * T_DIM];   // coalesced across t
        const float va = vs[a];
        #pragma unroll
        for (int s = 0; s < S_TILE; ++s) {
            const float x = ip_s[s][a] + mp;
            // tanh(x) = 1 - 2/(exp(2x)+1); handles +-inf correctly via rcp
            const float e  = __expf(2.f * x);
            const float th = fmaf(-2.f, __builtin_amdgcn_rcpf(e + 1.f), 1.f);
            acc[s] = fmaf(va, th, acc[s]);
        }
    }

    const bool valid = (mask[t * B_DIM + b] != 0);

    // ---- softmax over t (256 threads = 4 waves) per s ----
    #pragma unroll
    for (int s = 0; s < S_TILE; ++s) {
        const float masked = valid ? acc[s] : NEG_INF_F;
        float wm = warp_red_max(masked);
        if (lane == 0) red[wave] = wm;
        __syncthreads();
        const float m = fmaxf(fmaxf(red[0], red[1]), fmaxf(red[2], red[3]));
        const float e = __expf(masked - m);
        float ws = warp_red_sum(e);
        __syncthreads();                 // all reads of red (max) done
        if (lane == 0) red[wave] = ws;
        __syncthreads();
        const float sum = red[0] + red[1] + red[2] + red[3];
        sc[s][t] = e * __builtin_amdgcn_rcpf(sum);
        __syncthreads();                 // red free for next s; sc visible later
    }

    // ---- Phase 2: context. thread tid = feature d. ----
    const int d = tid;
    float ctx[S_TILE];
    #pragma unroll
    for (int s = 0; s < S_TILE; ++s) ctx[s] = 0.f;

    #pragma unroll 4
    for (int t2 = 0; t2 < T_DIM; ++t2) {
        const float xv = input[(t2 * B_DIM + b) * DIN + d];  // coalesced across d
        #pragma unroll
        for (int s = 0; s < S_TILE; ++s)
            ctx[s] = fmaf(sc[s][t2], xv, ctx[s]);
    }

    #pragma unroll
    for (int s = 0; s < S_TILE; ++s) {
        const int srow = s0 + s;
        out[((size_t)(srow * B_DIM + b)) * (2 * DIN) + d]       = ctx[s];
        out[((size_t)(srow * B_DIM + b)) * (2 * DIN) + DIN + d] = input[(srow * B_DIM + b) * DIN + d];
    }
}

extern "C" void kernel_launch(void* const* d_in, const int* in_sizes, int n_in,
                              void* d_out, int out_size, void* d_ws, size_t ws_size,
                              hipStream_t stream) {
    const float* input  = (const float*)d_in[0];
    const float* memory = (const float*)d_in[1];
    const int*   mask   = (const int*)d_in[2];
    const float* Wi     = (const float*)d_in[3];
    const float* Wm     = (const float*)d_in[4];
    const float* v      = (const float*)d_in[5];
    float* out = (float*)d_out;

    float* IP  = (float*)d_ws;                         // [T,B,A]  1 MB
    float* MPt = IP + (size_t)T_DIM * B_DIM * A_DIM;   // [B,A,T]  1 MB

    proj_kernel<<<T_DIM * B_DIM, 256, 0, stream>>>(input, memory, Wi, Wm, IP, MPt);
    attn_kernel<<<(T_DIM / S_TILE) * B_DIM, 256, 0, stream>>>(input, mask, v, IP, MPt, out);
}

// Round 3
// 110.793 us; speedup vs baseline: 1.0502x; 1.0502x over previous
//
#include <hip/hip_runtime.h>

#define T_DIM 256
#define B_DIM 8
#define DIN   256
#define DM    256
#define A_DIM 128
#define S_TILE 2
#define NEG_INF_F (-1e30f)
// pre-scale factor: tanh(x) needs exp(2x); v_exp_f32 computes 2^y, so store
// projections scaled by 2*log2(e) and use exp2 directly.
#define PRESCALE 2.885390081777927f

// ---------------- Kernel A: projections (pre-scaled) ----------------
__global__ __launch_bounds__(256) void proj_kernel(
    const float* __restrict__ input, const float* __restrict__ memory,
    const float* __restrict__ Wi, const float* __restrict__ Wm,
    float* __restrict__ IP, float* __restrict__ MPt)
{
    __shared__ float xin[DIN];
    __shared__ float xmem[DM];
    const int tb  = blockIdx.x;
    const int t   = tb / B_DIM;
    const int b   = tb % B_DIM;
    const int tid = threadIdx.x;

    xin[tid]  = input[(t * B_DIM + b) * DIN + tid];
    xmem[tid] = memory[(t * B_DIM + b) * DM + tid];
    __syncthreads();

    if (tid < A_DIM) {
        const int a = tid;
        float acc = 0.f;
        #pragma unroll 8
        for (int d = 0; d < DIN; ++d)
            acc = fmaf(xin[d], Wi[d * A_DIM + a], acc);
        IP[(t * B_DIM + b) * A_DIM + a] = acc * PRESCALE;
    } else {
        const int a = tid - A_DIM;
        float acc = 0.f;
        #pragma unroll 8
        for (int d = 0; d < DM; ++d)
            acc = fmaf(xmem[d], Wm[d * A_DIM + a], acc);
        MPt[(b * A_DIM + a) * T_DIM + t] = acc * PRESCALE;
    }
}

__device__ inline float warp_red_max(float v) {
    #pragma unroll
    for (int o = 32; o > 0; o >>= 1) v = fmaxf(v, __shfl_xor(v, o, 64));
    return v;
}
__device__ inline float warp_red_sum(float v) {
    #pragma unroll
    for (int o = 32; o > 0; o >>= 1) v += __shfl_xor(v, o, 64);
    return v;
}

// ---------------- Kernel B: logits + softmax + context + concat ----------------
// block per (b, s-tile of S_TILE). 256 threads = 4 waves.
__global__ __launch_bounds__(256) void attn_kernel(
    const float* __restrict__ input, const int* __restrict__ mask,
    const float* __restrict__ v, const float* __restrict__ IP,
    const float* __restrict__ MPt, float* __restrict__ out)
{
    __shared__ float ip_s[S_TILE][A_DIM];
    __shared__ float vs[A_DIM];
    __shared__ float sc[S_TILE][T_DIM];
    __shared__ float redm[S_TILE][4];

    const int blk = blockIdx.x;
    const int b   = blk % B_DIM;          // same-b blocks land on same XCD (L2 locality)
    const int s0  = (blk / B_DIM) * S_TILE;
    const int tid = threadIdx.x;
    const int lane = tid & 63;
    const int wave = tid >> 6;

    if (tid < A_DIM) vs[tid] = v[tid];
    for (int i = tid; i < S_TILE * A_DIM; i += 256) {
        const int s = i / A_DIM, a = i % A_DIM;
        ip_s[s][a] = IP[((s0 + s) * B_DIM + b) * A_DIM + a];
    }
    __syncthreads();

    // ---- Phase 1: logits. thread = key t.
    // tanh identity: v.tanh(x) summed = sumV - 2*sum(v*rcp(exp(2x)+1));
    // sumV is a constant shift -> cancels in softmax. logit_eff = -2*acc.
    const int t = tid;
    float acc0 = 0.f, acc1 = 0.f;
    const float* mp_base = MPt + (size_t)(b * A_DIM) * T_DIM + t;
    #pragma unroll 8
    for (int a = 0; a < A_DIM; ++a) {
        const float mp = mp_base[(size_t)a * T_DIM];   // coalesced across t
        const float va = vs[a];
        const float e0 = __builtin_amdgcn_exp2f(ip_s[0][a] + mp);
        const float e1 = __builtin_amdgcn_exp2f(ip_s[1][a] + mp);
        acc0 = fmaf(va, __builtin_amdgcn_rcpf(e0 + 1.f), acc0);
        acc1 = fmaf(va, __builtin_amdgcn_rcpf(e1 + 1.f), acc1);
    }

    const bool valid = (mask[t * B_DIM + b] != 0);
    const float l0 = valid ? (-2.f * acc0) : NEG_INF_F;
    const float l1 = valid ? (-2.f * acc1) : NEG_INF_F;

    // ---- softmax over t, both s rows fused (4 barriers total) ----
    float m0 = warp_red_max(l0), m1 = warp_red_max(l1);
    if (lane == 0) { redm[0][wave] = m0; redm[1][wave] = m1; }
    __syncthreads();
    m0 = fmaxf(fmaxf(redm[0][0], redm[0][1]), fmaxf(redm[0][2], redm[0][3]));
    m1 = fmaxf(fmaxf(redm[1][0], redm[1][1]), fmaxf(redm[1][2], redm[1][3]));
    const float e0 = __expf(l0 - m0);
    const float e1 = __expf(l1 - m1);
    float su0 = warp_red_sum(e0), su1 = warp_red_sum(e1);
    __syncthreads();
    if (lane == 0) { redm[0][wave] = su0; redm[1][wave] = su1; }
    __syncthreads();
    su0 = (redm[0][0] + redm[0][1]) + (redm[0][2] + redm[0][3]);
    su1 = (redm[1][0] + redm[1][1]) + (redm[1][2] + redm[1][3]);
    sc[0][t] = e0 * __builtin_amdgcn_rcpf(su0);
    sc[1][t] = e1 * __builtin_amdgcn_rcpf(su1);
    __syncthreads();

    // ---- Phase 2: context. thread = feature d. ----
    const int d = tid;
    float c0 = 0.f, c1 = 0.f;
    const float* in_b = input + b * DIN + d;
    #pragma unroll 8
    for (int t2 = 0; t2 < T_DIM; ++t2) {
        const float xv = in_b[(size_t)t2 * B_DIM * DIN];   // coalesced across d
        c0 = fmaf(sc[0][t2], xv, c0);
        c1 = fmaf(sc[1][t2], xv, c1);
    }

    {
        const int r0 = (s0 + 0) * B_DIM + b;
        const int r1 = (s0 + 1) * B_DIM + b;
        out[(size_t)r0 * (2 * DIN) + d]        = c0;
        out[(size_t)r0 * (2 * DIN) + DIN + d]  = input[r0 * DIN + d];
        out[(size_t)r1 * (2 * DIN) + d]        = c1;
        out[(size_t)r1 * (2 * DIN) + DIN + d]  = input[r1 * DIN + d];
    }
}

extern "C" void kernel_launch(void* const* d_in, const int* in_sizes, int n_in,
                              void* d_out, int out_size, void* d_ws, size_t ws_size,
                              hipStream_t stream) {
    const float* input  = (const float*)d_in[0];
    const float* memory = (const float*)d_in[1];
    const int*   mask   = (const int*)d_in[2];
    const float* Wi     = (const float*)d_in[3];
    const float* Wm     = (const float*)d_in[4];
    const float* v      = (const float*)d_in[5];
    float* out = (float*)d_out;

    float* IP  = (float*)d_ws;                         // [T,B,A]  1 MB (pre-scaled)
    float* MPt = IP + (size_t)T_DIM * B_DIM * A_DIM;   // [B,A,T]  1 MB (pre-scaled)

    proj_kernel<<<T_DIM * B_DIM, 256, 0, stream>>>(input, memory, Wi, Wm, IP, MPt);
    attn_kernel<<<(T_DIM / S_TILE) * B_DIM, 256, 0, stream>>>(input, mask, v, IP, MPt, out);
}